// Round 1
// baseline (807.707 us; speedup 1.0000x reference)
//
#include <hip/hip_runtime.h>
#include <hip/hip_bf16.h>

typedef __attribute__((ext_vector_type(8))) short bf16x8;
typedef __attribute__((ext_vector_type(4))) float f32x4;

static __device__ __forceinline__ float bf2f(unsigned short u){
  return __uint_as_float(((unsigned)u) << 16);
}
static __device__ __forceinline__ unsigned short f2bf(float f){
  unsigned u = __float_as_uint(f);
  u += 0x7FFFu + ((u >> 16) & 1u);
  return (unsigned short)(u >> 16);
}

#define MFMA16(acc, a, b) (acc) = __builtin_amdgcn_mfma_f32_16x16x32_bf16((a),(b),(acc),0,0,0)

#define NB   8
#define NVRT 2562
#define MP   2624      /* rows padded to 41*64 */
#define NRB  41

// channel-last bf16 feature-map buffer bases (elements)
#define FT_B0 0ul
#define FT_B1 6422528ul
#define FT_B2 9633792ul
#define FT_B3 11239424ul
#define FT_TOT 12042240ul

// ---------------------------------------------------------------- transpose [B,C,H,W]f32 -> [B,HW,C]bf16
__global__ void k_transpose(const float* __restrict__ src, unsigned short* __restrict__ dst,
                            int C, int HW)
{
  __shared__ float tile[32][33];
  int b = blockIdx.z;
  int hw0 = blockIdx.x * 32, c0 = blockIdx.y * 32;
  int tx = threadIdx.x, ty = threadIdx.y;
  const float* s = src + (size_t)b * C * HW;
#pragma unroll
  for (int i = 0; i < 4; i++){
    int c = c0 + ty + i*8, hw = hw0 + tx;
    tile[ty + i*8][tx] = (c < C && hw < HW) ? s[(size_t)c * HW + hw] : 0.f;
  }
  __syncthreads();
  unsigned short* d = dst + (size_t)b * HW * C;
#pragma unroll
  for (int i = 0; i < 4; i++){
    int hw = hw0 + ty + i*8, c = c0 + tx;
    if (hw < HW && c < C) d[(size_t)hw * C + c] = f2bf(tile[tx][ty + i*8]);
  }
}

// ---------------------------------------------------------------- bilinear metadata per (b,vert): 4 maps x {4 offsets,4 weights}
__global__ void k_meta(const float* __restrict__ pos, float* __restrict__ meta)
{
  int t = blockIdx.x * blockDim.x + threadIdx.x;
  if (t >= NB * NVRT) return;
  int b = t / NVRT;
  float px = pos[(size_t)t*3 + 0], py = pos[(size_t)t*3 + 1];
  px = fminf(fmaxf(px, -1.f), 1.f);
  py = fminf(fmaxf(py, -1.f), 1.f);
  const int    Wm[4]  = {56, 28, 14, 7};
  const int    Cm[4]  = {256, 512, 1024, 2048};
  const int    HWm[4] = {3136, 784, 196, 49};
  const size_t Bm[4]  = {FT_B0, FT_B1, FT_B2, FT_B3};
  float* mo = meta + (size_t)t * 32;
#pragma unroll
  for (int i = 0; i < 4; i++){
    int W = Wm[i], C = Cm[i];
    float gx = (px + 1.f) * 0.5f * (float)(W - 1);
    float gy = (py + 1.f) * 0.5f * (float)(W - 1);   // H==W for all maps
    int x0 = (int)floorf(gx), y0 = (int)floorf(gy);
    float wx = gx - (float)x0, wy = gy - (float)y0;
    int x1i = min(x0 + 1, W - 1), y1i = min(y0 + 1, W - 1);
    size_t base = Bm[i] + (size_t)b * HWm[i] * C;
    mo[i*8+0] = __int_as_float((int)(base + ((size_t)y0  * W + x0 ) * C));
    mo[i*8+1] = __int_as_float((int)(base + ((size_t)y0  * W + x1i) * C));
    mo[i*8+2] = __int_as_float((int)(base + ((size_t)y1i * W + x0 ) * C));
    mo[i*8+3] = __int_as_float((int)(base + ((size_t)y1i * W + x1i) * C));
    mo[i*8+4] = (1.f-wx)*(1.f-wy);
    mo[i*8+5] = wx*(1.f-wy);
    mo[i*8+6] = (1.f-wx)*wy;
    mo[i*8+7] = wx*wy;
  }
}

// ---------------------------------------------------------------- pack weight [Ksrc,Nsrc]f32 (cols 0..127) -> [Kp/8][128][8] bf16, zero-pad k>=Ksrc
__global__ void k_packw(const float* __restrict__ src, unsigned short* __restrict__ dst,
                        int Ksrc, int Nsrc, int Kp)
{
  int t = blockIdx.x * blockDim.x + threadIdx.x;
  if (t >= Kp * 128) return;
  int k = t >> 7, c = t & 127;
  float v = (k < Ksrc) ? src[(size_t)k * Nsrc + c] : 0.f;
  dst[((size_t)(k >> 3) * 128 + c) * 8 + (k & 7)] = f2bf(v);
}

// ---------------------------------------------------------------- fill vf base cols + zero pads of vf/x1/x2
__global__ void k_vf_base(const float* __restrict__ vfeat, const float* __restrict__ pos,
                          unsigned short* __restrict__ vf,
                          unsigned short* __restrict__ x1,
                          unsigned short* __restrict__ x2)
{
  int row = blockIdx.x, b = blockIdx.y;
  size_t vfo = ((size_t)b * MP + row) * 288;
  size_t xo  = ((size_t)b * MP + row) * 160;
  if (row < NVRT){
    size_t src = (size_t)b * NVRT + row;
    for (int c = threadIdx.x; c < 288; c += blockDim.x){
      if (c < 128)       vf[vfo + c] = f2bf(vfeat[src*128 + c]);
      else if (c < 131)  vf[vfo + c] = f2bf(pos[src*3 + (c - 128)]);
      else if (c >= 259) vf[vfo + c] = 0;
    }
    for (int c = threadIdx.x; c < 160; c += blockDim.x){
      if (c < 3){
        unsigned short v = f2bf(pos[src*3 + c]);
        x1[xo + c] = v; x2[xo + c] = v;
      } else if (c >= 131){
        x1[xo + c] = 0; x2[xo + c] = 0;
      }
    }
  } else {
    for (int c = threadIdx.x; c < 288; c += blockDim.x) vf[vfo + c] = 0;
    for (int c = threadIdx.x; c < 160; c += blockDim.x){ x1[xo + c] = 0; x2[xo + c] = 0; }
  }
}

// ---------------------------------------------------------------- fused vert_align + (verts @ w_lin0 + b) -> vf[:,131:259] bf16
__global__ __launch_bounds__(256) void k_lin0(
    const unsigned short* __restrict__ ftT,
    const float* __restrict__ meta,
    const unsigned short* __restrict__ wp,
    const float* __restrict__ bias,
    unsigned short* __restrict__ vf)
{
  __shared__ __align__(16) unsigned short atile[64 * 64];
  __shared__ float smeta[64][33];
  int b = blockIdx.y, rb = blockIdx.x * 64;
  int t = threadIdx.x;
  for (int i = t; i < 64 * 32; i += 256){
    int v = i >> 5, q = i & 31;
    int row = rb + v;
    smeta[v][q] = (row < NVRT) ? meta[((size_t)b * NVRT + row) * 32 + q] : 0.f;
  }
  __syncthreads();

  int wave = t >> 6, lane = t & 63;
  int vrow = t >> 2, chunk = t & 3;
  bool valid = (rb + vrow) < NVRT;
  f32x4 acc[8];
#pragma unroll
  for (int c = 0; c < 8; c++) acc[c] = (f32x4){0.f,0.f,0.f,0.f};

  int cur_m = -1;
  int o00=0,o01=0,o10=0,o11=0;
  float w00=0,w01=0,w10=0,w11=0;
  int arow = wave * 16 + (lane & 15);
  int sw = (arow & 7) << 4;
  int wsw = (vrow & 7) << 4;

  for (int k0 = 0; k0 < 3840; k0 += 64){
    int m = (k0 < 256) ? 0 : (k0 < 768) ? 1 : (k0 < 1792) ? 2 : 3;
    if (m != cur_m){
      cur_m = m;
      o00 = __float_as_int(smeta[vrow][m*8+0]);
      o01 = __float_as_int(smeta[vrow][m*8+1]);
      o10 = __float_as_int(smeta[vrow][m*8+2]);
      o11 = __float_as_int(smeta[vrow][m*8+3]);
      w00 = smeta[vrow][m*8+4];
      w01 = smeta[vrow][m*8+5];
      w10 = smeta[vrow][m*8+6];
      w11 = smeta[vrow][m*8+7];
    }
    int koff = (m==0) ? 0 : (m==1) ? 256 : (m==2) ? 768 : 1792;
    int kk0 = (k0 - koff) + chunk * 16;
    bf16x8 h0, h1;
    if (valid){
      const bf16x8* p00 = (const bf16x8*)(ftT + o00 + kk0);
      const bf16x8* p01 = (const bf16x8*)(ftT + o01 + kk0);
      const bf16x8* p10 = (const bf16x8*)(ftT + o10 + kk0);
      const bf16x8* p11 = (const bf16x8*)(ftT + o11 + kk0);
      bf16x8 a0 = p00[0], b0v = p01[0], c0v = p10[0], d0v = p11[0];
      bf16x8 a1 = p00[1], b1v = p01[1], c1v = p10[1], d1v = p11[1];
#pragma unroll
      for (int e = 0; e < 8; e++){
        float f = w00*bf2f((unsigned short)a0[e]) + w01*bf2f((unsigned short)b0v[e])
                + w10*bf2f((unsigned short)c0v[e]) + w11*bf2f((unsigned short)d0v[e]);
        h0[e] = (short)f2bf(f);
      }
#pragma unroll
      for (int e = 0; e < 8; e++){
        float f = w00*bf2f((unsigned short)a1[e]) + w01*bf2f((unsigned short)b1v[e])
                + w10*bf2f((unsigned short)c1v[e]) + w11*bf2f((unsigned short)d1v[e]);
        h1[e] = (short)f2bf(f);
      }
    } else {
#pragma unroll
      for (int e = 0; e < 8; e++){ h0[e] = 0; h1[e] = 0; }
    }
    char* basep = (char*)atile + vrow * 128;
    *(bf16x8*)(basep + ((chunk*32     ) ^ wsw)) = h0;
    *(bf16x8*)(basep + ((chunk*32 + 16) ^ wsw)) = h1;
    __syncthreads();
#pragma unroll
    for (int ks = 0; ks < 2; ks++){
      bf16x8 a = *(const bf16x8*)((const char*)atile + arow*128 + ((ks*64 + (lane>>4)*16) ^ sw));
      int kb = k0 + ks * 32;
      const unsigned short* bp = wp + ((size_t)((kb>>3) + (lane>>4)) * 128 + (lane & 15)) * 8;
#pragma unroll
      for (int c = 0; c < 8; c++){
        bf16x8 bb = *(const bf16x8*)(bp + c * 128);
        MFMA16(acc[c], a, bb);
      }
    }
    __syncthreads();
  }
#pragma unroll
  for (int c = 0; c < 8; c++){
    int col = 16*c + (lane & 15);
    float bv = bias[col];
#pragma unroll
    for (int r = 0; r < 4; r++){
      int row = rb + wave*16 + (lane>>4)*4 + r;
      if (row < NVRT)
        vf[((size_t)b * MP + row) * 288 + 131 + col] = f2bf(acc[c][r] + bv);
    }
  }
}

// ---------------------------------------------------------------- y0 = x@w0 (f32), y1p = pack(x@w1) (bf16)
template<int KX>
__global__ __launch_bounds__(256) void k_xw(
    const unsigned short* __restrict__ x,
    const unsigned short* __restrict__ wp0,
    const unsigned short* __restrict__ wp1,
    float* __restrict__ y0,
    unsigned short* __restrict__ y1p)
{
  int b = blockIdx.y, rb = blockIdx.x * 64;
  int t = threadIdx.x, wave = t >> 6, lane = t & 63;
  f32x4 acc0[8], acc1[8];
#pragma unroll
  for (int c = 0; c < 8; c++){ acc0[c] = (f32x4){0,0,0,0}; acc1[c] = (f32x4){0,0,0,0}; }
  int row = rb + wave*16 + (lane & 15);
  const unsigned short* xp = x + ((size_t)b * MP + row) * KX + (lane >> 4) * 8;
#pragma unroll
  for (int kb = 0; kb < KX; kb += 32){
    bf16x8 a = *(const bf16x8*)(xp + kb);
    size_t bo = ((size_t)((kb>>3) + (lane>>4)) * 128 + (lane & 15)) * 8;
#pragma unroll
    for (int c = 0; c < 8; c++){
      bf16x8 b0 = *(const bf16x8*)(wp0 + bo + c*128);
      MFMA16(acc0[c], a, b0);
      bf16x8 b1 = *(const bf16x8*)(wp1 + bo + c*128);
      MFMA16(acc1[c], a, b1);
    }
  }
#pragma unroll
  for (int c = 0; c < 8; c++){
    int col = 16*c + (lane & 15);
#pragma unroll
    for (int r = 0; r < 4; r++){
      int orow = rb + wave*16 + (lane>>4)*4 + r;
      y0[((size_t)b * MP + orow) * 128 + col] = acc0[c][r];
      y1p[(((size_t)b * (MP/8) + (orow>>3)) * 128 + col) * 8 + (orow & 7)] = f2bf(acc1[c][r]);
    }
  }
}

// ---------------------------------------------------------------- h = relu(y0 + adj@y1); EPI=0 -> xnext bf16 cols 3..130, EPI=1 -> d_out f32
template<int EPI>
__global__ __launch_bounds__(256) void k_adj(
    const float* __restrict__ adj,
    const unsigned short* __restrict__ y1p,
    const float* __restrict__ y0,
    unsigned short* __restrict__ xnext,
    float* __restrict__ outf)
{
  __shared__ __align__(16) unsigned short atile[64 * 64];
  int b = blockIdx.y, rb = blockIdx.x * 64;
  int t = threadIdx.x, wave = t >> 6, lane = t & 63;
  f32x4 acc[8];
#pragma unroll
  for (int c = 0; c < 8; c++) acc[c] = (f32x4){0,0,0,0};
  int vrow = t >> 2, chunk = t & 3;
  int grow = rb + vrow;
  bool rvalid = grow < NVRT;
  const float* ap = adj + ((size_t)b * NVRT + grow) * NVRT;
  const unsigned short* y1b = y1p + (size_t)b * (MP/8) * 128 * 8;
  int arow = wave*16 + (lane & 15);
  int sw = (arow & 7) << 4;
  int wsw = (vrow & 7) << 4;

  for (int k0 = 0; k0 < MP; k0 += 64){
    float vals[16];
    int jbase = k0 + chunk * 16;
    if (rvalid && (jbase + 16 <= NVRT)){
      const float2* p = (const float2*)(ap + jbase);
#pragma unroll
      for (int e = 0; e < 8; e++){ float2 f = p[e]; vals[2*e] = f.x; vals[2*e+1] = f.y; }
    } else {
#pragma unroll
      for (int e = 0; e < 16; e++){
        int j = jbase + e;
        vals[e] = (rvalid && j < NVRT) ? ap[j] : 0.f;
      }
    }
    bf16x8 h0, h1;
#pragma unroll
    for (int e = 0; e < 8; e++) h0[e] = (short)f2bf(vals[e]);
#pragma unroll
    for (int e = 0; e < 8; e++) h1[e] = (short)f2bf(vals[8+e]);
    char* basep = (char*)atile + vrow * 128;
    *(bf16x8*)(basep + ((chunk*32     ) ^ wsw)) = h0;
    *(bf16x8*)(basep + ((chunk*32 + 16) ^ wsw)) = h1;
    __syncthreads();
#pragma unroll
    for (int ks = 0; ks < 2; ks++){
      bf16x8 a = *(const bf16x8*)((const char*)atile + arow*128 + ((ks*64 + (lane>>4)*16) ^ sw));
      int kb = k0 + ks*32;
      const unsigned short* bp = y1b + ((size_t)((kb>>3) + (lane>>4)) * 128 + (lane & 15)) * 8;
#pragma unroll
      for (int c = 0; c < 8; c++){
        bf16x8 bb = *(const bf16x8*)(bp + c*128);
        MFMA16(acc[c], a, bb);
      }
    }
    __syncthreads();
  }
#pragma unroll
  for (int c = 0; c < 8; c++){
    int col = 16*c + (lane & 15);
#pragma unroll
    for (int r = 0; r < 4; r++){
      int row = rb + wave*16 + (lane>>4)*4 + r;
      if (row < NVRT){
        float v = fmaxf(y0[((size_t)b*MP + row)*128 + col] + acc[c][r], 0.f);
        if (EPI == 0) xnext[((size_t)b*MP + row)*160 + 3 + col] = f2bf(v);
        else          outf[((size_t)b*NVRT + row)*128 + col] = v;
      }
    }
  }
}

// ---------------------------------------------------------------- new_pos = pos + tanh(feat @ w_lin1 + b_lin1)
__global__ void k_lin1(const float* __restrict__ feat, const float* __restrict__ pos,
                       const float* __restrict__ w, const float* __restrict__ bias,
                       float* __restrict__ opos)
{
  int t = blockIdx.x * blockDim.x + threadIdx.x;
  if (t >= NB * NVRT) return;
  const float* f = feat + (size_t)t * 128;
  float a0 = bias[0], a1 = bias[1], a2 = bias[2];
#pragma unroll 4
  for (int k = 0; k < 128; k++){
    float fv = f[k];
    a0 += fv * w[k*3+0];
    a1 += fv * w[k*3+1];
    a2 += fv * w[k*3+2];
  }
  opos[(size_t)t*3+0] = pos[(size_t)t*3+0] + tanhf(a0);
  opos[(size_t)t*3+1] = pos[(size_t)t*3+1] + tanhf(a1);
  opos[(size_t)t*3+2] = pos[(size_t)t*3+2] + tanhf(a2);
}

// ================================================================ host
extern "C" void kernel_launch(void* const* d_in, const int* in_sizes, int n_in,
                              void* d_out, int out_size, void* d_ws, size_t ws_size,
                              hipStream_t stream)
{
  const float* conv[4] = {(const float*)d_in[0], (const float*)d_in[1],
                          (const float*)d_in[2], (const float*)d_in[3]};
  const float* adj   = (const float*)d_in[4];
  const float* pos   = (const float*)d_in[5];
  const float* vfeat = (const float*)d_in[6];
  const float* wlin0 = (const float*)d_in[7];
  const float* blin0 = (const float*)d_in[8];
  const float* gw[6] = {(const float*)d_in[9],  (const float*)d_in[10],
                        (const float*)d_in[11], (const float*)d_in[12],
                        (const float*)d_in[13], (const float*)d_in[14]};
  const float* wlin1 = (const float*)d_in[15];
  const float* blin1 = (const float*)d_in[16];

  char* ws = (char*)d_ws;
  size_t off = 0;
  auto take = [&](size_t bytes)->char* {
    char* p = ws + off;
    off += (bytes + 255) & ~(size_t)255;
    return p;
  };
  unsigned short* ftT  = (unsigned short*)take(FT_TOT * 2);
  float*          meta = (float*)take((size_t)NB*NVRT*32*4);
  unsigned short* wl0p = (unsigned short*)take((size_t)3840*128*2);
  unsigned short* w0p0 = (unsigned short*)take((size_t)288*128*2);
  unsigned short* w1p0 = (unsigned short*)take((size_t)288*128*2);
  unsigned short* w0p1 = (unsigned short*)take((size_t)160*128*2);
  unsigned short* w1p1 = (unsigned short*)take((size_t)160*128*2);
  unsigned short* w0p2 = (unsigned short*)take((size_t)160*128*2);
  unsigned short* w1p2 = (unsigned short*)take((size_t)160*128*2);
  unsigned short* vf   = (unsigned short*)take((size_t)NB*MP*288*2);
  unsigned short* x1   = (unsigned short*)take((size_t)NB*MP*160*2);
  unsigned short* x2   = (unsigned short*)take((size_t)NB*MP*160*2);
  float*          y0   = (float*)take((size_t)NB*MP*128*4);
  unsigned short* y1p  = (unsigned short*)take((size_t)NB*MP*128*2);

  float* out_pos  = (float*)d_out;
  float* out_feat = out_pos + (size_t)NB*NVRT*3;

  // 1. transpose conv maps to channel-last bf16
  const size_t ftBase[4] = {FT_B0, FT_B1, FT_B2, FT_B3};
  const int mC[4]  = {256, 512, 1024, 2048};
  const int mHW[4] = {3136, 784, 196, 49};
  for (int m = 0; m < 4; m++){
    dim3 g((mHW[m] + 31) / 32, (mC[m] + 31) / 32, NB);
    k_transpose<<<g, dim3(32, 8), 0, stream>>>(conv[m], ftT + ftBase[m], mC[m], mHW[m]);
  }
  // 2. bilinear metadata
  k_meta<<<(NB*NVRT + 255)/256, 256, 0, stream>>>(pos, meta);
  // 3. weight packing (zero-padded K)
  k_packw<<<(3840*128 + 255)/256, 256, 0, stream>>>(wlin0, wl0p, 3840, 128, 3840);
  k_packw<<<(288*128  + 255)/256, 256, 0, stream>>>(gw[0], w0p0, 259, 131, 288);
  k_packw<<<(288*128  + 255)/256, 256, 0, stream>>>(gw[1], w1p0, 259, 131, 288);
  k_packw<<<(160*128  + 255)/256, 256, 0, stream>>>(gw[2], w0p1, 131, 128, 160);
  k_packw<<<(160*128  + 255)/256, 256, 0, stream>>>(gw[3], w1p1, 131, 128, 160);
  k_packw<<<(160*128  + 255)/256, 256, 0, stream>>>(gw[4], w0p2, 131, 128, 160);
  k_packw<<<(160*128  + 255)/256, 256, 0, stream>>>(gw[5], w1p2, 131, 128, 160);
  // 4. vf base columns + zero pads (also zeroes pad rows -> no NaN leakage)
  k_vf_base<<<dim3(MP, NB), 64, 0, stream>>>(vfeat, pos, vf, x1, x2);
  // 5. fused vert_align + lin0 -> vf[:,131:259]
  k_lin0<<<dim3(NRB, NB), 256, 0, stream>>>(ftT, meta, wl0p, blin0, vf);
  // 6-11. three graph convs (N=128 effective everywhere)
  k_xw<288><<<dim3(NRB, NB), 256, 0, stream>>>(vf, w0p0, w1p0, y0, y1p);
  k_adj<0> <<<dim3(NRB, NB), 256, 0, stream>>>(adj, y1p, y0, x1, nullptr);
  k_xw<160><<<dim3(NRB, NB), 256, 0, stream>>>(x1, w0p1, w1p1, y0, y1p);
  k_adj<0> <<<dim3(NRB, NB), 256, 0, stream>>>(adj, y1p, y0, x2, nullptr);
  k_xw<160><<<dim3(NRB, NB), 256, 0, stream>>>(x2, w0p2, w1p2, y0, y1p);
  k_adj<1> <<<dim3(NRB, NB), 256, 0, stream>>>(adj, y1p, y0, nullptr, out_feat);
  // 12. position head
  k_lin1<<<(NB*NVRT + 255)/256, 256, 0, stream>>>(out_feat, pos, wlin1, blin1, out_pos);
  (void)in_sizes; (void)n_in; (void)out_size; (void)ws_size;
}

// Round 2
// 374.916 us; speedup vs baseline: 2.1544x; 2.1544x over previous
//
#include <hip/hip_runtime.h>
#include <hip/hip_bf16.h>

typedef __attribute__((ext_vector_type(8))) short bf16x8;
typedef __attribute__((ext_vector_type(4))) float f32x4;

static __device__ __forceinline__ float bf2f(unsigned short u){
  return __uint_as_float(((unsigned)u) << 16);
}
static __device__ __forceinline__ unsigned short f2bf(float f){
  unsigned u = __float_as_uint(f);
  u += 0x7FFFu + ((u >> 16) & 1u);
  return (unsigned short)(u >> 16);
}
static __device__ __forceinline__ void gload_lds16(const void* g, void* l){
  __builtin_amdgcn_global_load_lds((const __attribute__((address_space(1))) unsigned int*)g,
                                   (__attribute__((address_space(3))) unsigned int*)l, 16, 0, 0);
}

#define MFMA16(acc, a, b) (acc) = __builtin_amdgcn_mfma_f32_16x16x32_bf16((a),(b),(acc),0,0,0)

#define NB   8
#define NVRT 2562
#define MP   2624      /* rows padded to 41*64 = 82*32 */
#define NRB  41        /* 64-row blocks (fallback) */
#define NRB2 82        /* 32-row blocks */
#define NKT  41        /* K tiles of 64 over MP */

// channel-last bf16 feature-map buffer bases (elements)
#define FT_B0 0ul
#define FT_B1 6422528ul
#define FT_B2 9633792ul
#define FT_B3 11239424ul
#define FT_TOT 12042240ul

// ---------------------------------------------------------------- transpose [B,C,H,W]f32 -> [B,HW,C]bf16
__global__ void k_transpose(const float* __restrict__ src, unsigned short* __restrict__ dst,
                            int C, int HW)
{
  __shared__ float tile[32][33];
  int b = blockIdx.z;
  int hw0 = blockIdx.x * 32, c0 = blockIdx.y * 32;
  int tx = threadIdx.x, ty = threadIdx.y;
  const float* s = src + (size_t)b * C * HW;
#pragma unroll
  for (int i = 0; i < 4; i++){
    int c = c0 + ty + i*8, hw = hw0 + tx;
    tile[ty + i*8][tx] = (c < C && hw < HW) ? s[(size_t)c * HW + hw] : 0.f;
  }
  __syncthreads();
  unsigned short* d = dst + (size_t)b * HW * C;
#pragma unroll
  for (int i = 0; i < 4; i++){
    int hw = hw0 + ty + i*8, c = c0 + tx;
    if (hw < HW && c < C) d[(size_t)hw * C + c] = f2bf(tile[tx][ty + i*8]);
  }
}

// ---------------------------------------------------------------- bilinear metadata per (b,vert)
__global__ void k_meta(const float* __restrict__ pos, float* __restrict__ meta)
{
  int t = blockIdx.x * blockDim.x + threadIdx.x;
  if (t >= NB * NVRT) return;
  int b = t / NVRT;
  float px = pos[(size_t)t*3 + 0], py = pos[(size_t)t*3 + 1];
  px = fminf(fmaxf(px, -1.f), 1.f);
  py = fminf(fmaxf(py, -1.f), 1.f);
  const int    Wm[4]  = {56, 28, 14, 7};
  const int    Cm[4]  = {256, 512, 1024, 2048};
  const int    HWm[4] = {3136, 784, 196, 49};
  const size_t Bm[4]  = {FT_B0, FT_B1, FT_B2, FT_B3};
  float* mo = meta + (size_t)t * 32;
#pragma unroll
  for (int i = 0; i < 4; i++){
    int W = Wm[i], C = Cm[i];
    float gx = (px + 1.f) * 0.5f * (float)(W - 1);
    float gy = (py + 1.f) * 0.5f * (float)(W - 1);
    int x0 = (int)floorf(gx), y0 = (int)floorf(gy);
    float wx = gx - (float)x0, wy = gy - (float)y0;
    int x1i = min(x0 + 1, W - 1), y1i = min(y0 + 1, W - 1);
    size_t base = Bm[i] + (size_t)b * HWm[i] * C;
    mo[i*8+0] = __int_as_float((int)(base + ((size_t)y0  * W + x0 ) * C));
    mo[i*8+1] = __int_as_float((int)(base + ((size_t)y0  * W + x1i) * C));
    mo[i*8+2] = __int_as_float((int)(base + ((size_t)y1i * W + x0 ) * C));
    mo[i*8+3] = __int_as_float((int)(base + ((size_t)y1i * W + x1i) * C));
    mo[i*8+4] = (1.f-wx)*(1.f-wy);
    mo[i*8+5] = wx*(1.f-wy);
    mo[i*8+6] = (1.f-wx)*wy;
    mo[i*8+7] = wx*wy;
  }
}

// ---------------------------------------------------------------- pack weight [Ksrc,Nsrc]f32 (cols 0..127) -> [Kp/8][128][8] bf16
__global__ void k_packw(const float* __restrict__ src, unsigned short* __restrict__ dst,
                        int Ksrc, int Nsrc, int Kp)
{
  int t = blockIdx.x * blockDim.x + threadIdx.x;
  if (t >= Kp * 128) return;
  int k = t >> 7, c = t & 127;
  float v = (k < Ksrc) ? src[(size_t)k * Nsrc + c] : 0.f;
  dst[((size_t)(k >> 3) * 128 + c) * 8 + (k & 7)] = f2bf(v);
}

// ---------------------------------------------------------------- pack adjacency f32 -> bf16 MFMA tiles with baked XOR swizzle
// layout: [B][82 rowblk][41 ktile] of 4KB tiles; tile byte = row*128 + ((k8*16) ^ ((row&7)<<4))
__global__ void k_adjpack(const float* __restrict__ adj, unsigned short* __restrict__ adjP)
{
  int kt = blockIdx.x, rb = blockIdx.y, b = blockIdx.z;
  int t = threadIdx.x, row = t >> 3, k8 = t & 7;
  int grow = rb*32 + row, gk = kt*64 + k8*8;
  unsigned short o[8];
  if (grow < NVRT && gk + 8 <= NVRT){
    const float2* p = (const float2*)(adj + ((size_t)b*NVRT + grow)*NVRT + gk);
    float2 f0 = p[0], f1 = p[1], f2 = p[2], f3 = p[3];
    o[0]=f2bf(f0.x); o[1]=f2bf(f0.y); o[2]=f2bf(f1.x); o[3]=f2bf(f1.y);
    o[4]=f2bf(f2.x); o[5]=f2bf(f2.y); o[6]=f2bf(f3.x); o[7]=f2bf(f3.y);
  } else if (grow < NVRT){
    const float* ap = adj + ((size_t)b*NVRT + grow)*NVRT;
#pragma unroll
    for (int e = 0; e < 8; e++){ int k = gk + e; o[e] = (k < NVRT) ? f2bf(ap[k]) : 0; }
  } else {
#pragma unroll
    for (int e = 0; e < 8; e++) o[e] = 0;
  }
  bf16x8 h;
#pragma unroll
  for (int e = 0; e < 8; e++) h[e] = (short)o[e];
  char* tb = (char*)(adjP + (((size_t)b*NRB2 + rb)*NKT + kt) * 2048);
  *(bf16x8*)(tb + row*128 + ((k8*16) ^ ((row&7)<<4))) = h;
}

// ---------------------------------------------------------------- fill vf base cols + zero pads of vf/x1/x2
__global__ void k_vf_base(const float* __restrict__ vfeat, const float* __restrict__ pos,
                          unsigned short* __restrict__ vf,
                          unsigned short* __restrict__ x1,
                          unsigned short* __restrict__ x2)
{
  int row = blockIdx.x, b = blockIdx.y;
  size_t vfo = ((size_t)b * MP + row) * 288;
  size_t xo  = ((size_t)b * MP + row) * 160;
  if (row < NVRT){
    size_t src = (size_t)b * NVRT + row;
    for (int c = threadIdx.x; c < 288; c += blockDim.x){
      if (c < 128)       vf[vfo + c] = f2bf(vfeat[src*128 + c]);
      else if (c < 131)  vf[vfo + c] = f2bf(pos[src*3 + (c - 128)]);
      else if (c >= 259) vf[vfo + c] = 0;
    }
    for (int c = threadIdx.x; c < 160; c += blockDim.x){
      if (c < 3){
        unsigned short v = f2bf(pos[src*3 + c]);
        x1[xo + c] = v; x2[xo + c] = v;
      } else if (c >= 131){
        x1[xo + c] = 0; x2[xo + c] = 0;
      }
    }
  } else {
    for (int c = threadIdx.x; c < 288; c += blockDim.x) vf[vfo + c] = 0;
    for (int c = threadIdx.x; c < 160; c += blockDim.x){ x1[xo + c] = 0; x2[xo + c] = 0; }
  }
}

// ---------------------------------------------------------------- fused vert_align + lin0 (32-row tiles, reg-prefetch, dbuf LDS)
__global__ __launch_bounds__(256) void k_lin0b(
    const unsigned short* __restrict__ ftT,
    const float* __restrict__ meta,
    const unsigned short* __restrict__ wp,
    const float* __restrict__ bias,
    unsigned short* __restrict__ vf)
{
  __shared__ __align__(16) unsigned short abuf[2][2048];
  __shared__ float smeta[32][33];
  int b = blockIdx.y, rb = blockIdx.x * 32;
  int t = threadIdx.x, wave = t >> 6, lane = t & 63;
  for (int i = t; i < 1024; i += 256){
    int v = i >> 5, q = i & 31;
    int row = rb + v;
    smeta[v][q] = (row < NVRT) ? meta[((size_t)b * NVRT + row) * 32 + q] : 0.f;
  }
  __syncthreads();

  int srow = t >> 3, k8 = t & 7;
  bool valid = (rb + srow) < NVRT;
  int swst = (srow & 7) << 4;
  int l15 = lane & 15, l4 = lane >> 4;

  f32x4 acc[2][2];
#pragma unroll
  for (int i = 0; i < 2; i++)
#pragma unroll
    for (int j = 0; j < 2; j++) acc[i][j] = (f32x4){0,0,0,0};

  auto mapof = [](int kt){ return (kt < 4) ? 0 : (kt < 12) ? 1 : (kt < 28) ? 2 : 3; };

  auto issue = [&](int kt, bf16x8& A, bf16x8& Bv, bf16x8& C, bf16x8& D){
    int m = mapof(kt);
    int koff = (m==0) ? 0 : (m==1) ? 256 : (m==2) ? 768 : 1792;
    int kk = kt*64 - koff + k8*8;
    if (valid){
      int o00 = __float_as_int(smeta[srow][m*8+0]);
      int o01 = __float_as_int(smeta[srow][m*8+1]);
      int o10 = __float_as_int(smeta[srow][m*8+2]);
      int o11 = __float_as_int(smeta[srow][m*8+3]);
      A  = *(const bf16x8*)(ftT + o00 + kk);
      Bv = *(const bf16x8*)(ftT + o01 + kk);
      C  = *(const bf16x8*)(ftT + o10 + kk);
      D  = *(const bf16x8*)(ftT + o11 + kk);
    } else {
#pragma unroll
      for (int e = 0; e < 8; e++){ A[e]=0; Bv[e]=0; C[e]=0; D[e]=0; }
    }
  };

  auto blendwrite = [&](int kt, int bufi, bf16x8 A, bf16x8 Bv, bf16x8 C, bf16x8 D){
    int m = mapof(kt);
    float w00 = smeta[srow][m*8+4], w01 = smeta[srow][m*8+5];
    float w10 = smeta[srow][m*8+6], w11 = smeta[srow][m*8+7];
    bf16x8 h;
#pragma unroll
    for (int e = 0; e < 8; e++){
      float f = w00*bf2f((unsigned short)A[e]) + w01*bf2f((unsigned short)Bv[e])
              + w10*bf2f((unsigned short)C[e]) + w11*bf2f((unsigned short)D[e]);
      h[e] = (short)f2bf(f);
    }
    *(bf16x8*)((char*)&abuf[bufi][0] + srow*128 + ((k8*16) ^ swst)) = h;
  };

  auto compute = [&](int kt, int bufi){
    const char* ab = (const char*)&abuf[bufi][0];
    bf16x8 afr[2][2], bfr[2][2];
#pragma unroll
    for (int rf = 0; rf < 2; rf++){
      int row = rf*16 + l15;
      int sw = (row & 7) << 4;
#pragma unroll
      for (int ks = 0; ks < 2; ks++)
        afr[rf][ks] = *(const bf16x8*)(ab + row*128 + ((ks*64 + l4*16) ^ sw));
    }
#pragma unroll
    for (int cf = 0; cf < 2; cf++)
#pragma unroll
      for (int ks = 0; ks < 2; ks++)
        bfr[cf][ks] = *(const bf16x8*)(wp + ((size_t)(kt*8 + ks*4 + l4)*128 + wave*32 + cf*16 + l15)*8);
#pragma unroll
    for (int ks = 0; ks < 2; ks++)
#pragma unroll
      for (int rf = 0; rf < 2; rf++)
#pragma unroll
        for (int cf = 0; cf < 2; cf++)
          MFMA16(acc[rf][cf], afr[rf][ks], bfr[cf][ks]);
  };

  bf16x8 pA,pB,pC,pD, qA,qB,qC,qD;
  issue(0, pA,pB,pC,pD);
  for (int kt = 0; kt < 60; kt += 2){
    issue(kt+1, qA,qB,qC,qD);
    blendwrite(kt, 0, pA,pB,pC,pD);
    __syncthreads();
    compute(kt, 0);
    if (kt + 2 < 60) issue(kt+2, pA,pB,pC,pD);
    blendwrite(kt+1, 1, qA,qB,qC,qD);
    __syncthreads();
    compute(kt+1, 1);
  }

#pragma unroll
  for (int rf = 0; rf < 2; rf++)
#pragma unroll
    for (int cf = 0; cf < 2; cf++){
      int col = wave*32 + cf*16 + l15;
      float bv = bias[col];
#pragma unroll
      for (int r = 0; r < 4; r++){
        int row = rb + rf*16 + l4*4 + r;
        if (row < NVRT)
          vf[((size_t)b * MP + row) * 288 + 131 + col] = f2bf(acc[rf][cf][r] + bv);
      }
    }
}

// ---------------------------------------------------------------- y0 = x@w0 (f32), y1p = pack(x@w1) (32-row tiles)
template<int KX>
__global__ __launch_bounds__(256) void k_xw2(
    const unsigned short* __restrict__ x,
    const unsigned short* __restrict__ wp0,
    const unsigned short* __restrict__ wp1,
    float* __restrict__ y0,
    unsigned short* __restrict__ y1p)
{
  int b = blockIdx.y, rb = blockIdx.x * 32;
  int t = threadIdx.x, wave = t >> 6, lane = t & 63;
  int rf = wave & 1, ch = wave >> 1;
  int l15 = lane & 15, l4 = lane >> 4;
  f32x4 a0[4], a1[4];
#pragma unroll
  for (int c = 0; c < 4; c++){ a0[c] = (f32x4){0,0,0,0}; a1[c] = (f32x4){0,0,0,0}; }
  int row = rb + rf*16 + l15;
  const unsigned short* xp = x + ((size_t)b * MP + row) * KX + l4 * 8;
#pragma unroll
  for (int kb = 0; kb < KX; kb += 32){
    bf16x8 a = *(const bf16x8*)(xp + kb);
    size_t bo = ((size_t)((kb>>3) + l4) * 128 + ch*64 + l15) * 8;
#pragma unroll
    for (int c = 0; c < 4; c++){
      bf16x8 b0 = *(const bf16x8*)(wp0 + bo + c*128);
      MFMA16(a0[c], a, b0);
      bf16x8 b1 = *(const bf16x8*)(wp1 + bo + c*128);
      MFMA16(a1[c], a, b1);
    }
  }
#pragma unroll
  for (int c = 0; c < 4; c++){
    int col = ch*64 + c*16 + l15;
#pragma unroll
    for (int r = 0; r < 4; r++){
      int orow = rb + rf*16 + l4*4 + r;
      y0[((size_t)b * MP + orow) * 128 + col] = a0[c][r];
      y1p[(((size_t)b * (MP/8) + (orow>>3)) * 128 + col) * 8 + (orow & 7)] = f2bf(a1[c][r]);
    }
  }
}

// ---------------------------------------------------------------- h = relu(y0 + adj@y1) from PACKED bf16 adjacency
// 32-row tiles, global_load_lds staging, dbuf, 2-phase pipeline
template<int EPI>
__global__ __launch_bounds__(256) void k_adj2(
    const unsigned short* __restrict__ adjP,
    const unsigned short* __restrict__ y1p,
    const float* __restrict__ y0,
    unsigned short* __restrict__ xnext,
    float* __restrict__ outf)
{
  __shared__ __align__(16) unsigned short abuf[2][2048];
  int b = blockIdx.y, rb = blockIdx.x;
  int t = threadIdx.x, wave = t >> 6, lane = t & 63;
  int l15 = lane & 15, l4 = lane >> 4;
  const unsigned short* tbase = adjP + (((size_t)b*NRB2 + rb)*NKT) * 2048;
  const unsigned short* y1b = y1p + (size_t)b * (MP/8) * 128 * 8;

  f32x4 acc[2][2];
#pragma unroll
  for (int i = 0; i < 2; i++)
#pragma unroll
    for (int j = 0; j < 2; j++) acc[i][j] = (f32x4){0,0,0,0};

  auto stage = [&](int kt, int bufi){
    gload_lds16(tbase + (size_t)kt*2048 + t*8, &abuf[bufi][wave*512]);
  };

  stage(0, 0);
  __syncthreads();

  for (int kt = 0; kt < NKT; ++kt){
    int cur = kt & 1;
    if (kt < NKT-1) stage(kt+1, cur ^ 1);
    bf16x8 bfr[2][2];
#pragma unroll
    for (int cf = 0; cf < 2; cf++)
#pragma unroll
      for (int ks = 0; ks < 2; ks++)
        bfr[cf][ks] = *(const bf16x8*)(y1b + ((size_t)(kt*8 + ks*4 + l4)*128 + wave*32 + cf*16 + l15)*8);
    const char* ab = (const char*)&abuf[cur][0];
    bf16x8 afr[2][2];
#pragma unroll
    for (int rf = 0; rf < 2; rf++){
      int row = rf*16 + l15;
      int sw = (row & 7) << 4;
#pragma unroll
      for (int ks = 0; ks < 2; ks++)
        afr[rf][ks] = *(const bf16x8*)(ab + row*128 + ((ks*64 + l4*16) ^ sw));
    }
#pragma unroll
    for (int ks = 0; ks < 2; ks++)
#pragma unroll
      for (int rf = 0; rf < 2; rf++)
#pragma unroll
        for (int cf = 0; cf < 2; cf++)
          MFMA16(acc[rf][cf], afr[rf][ks], bfr[cf][ks]);
    __syncthreads();
  }

#pragma unroll
  for (int rf = 0; rf < 2; rf++)
#pragma unroll
    for (int cf = 0; cf < 2; cf++){
      int col = wave*32 + cf*16 + l15;
#pragma unroll
      for (int r = 0; r < 4; r++){
        int row = rb*32 + rf*16 + l4*4 + r;
        if (row < NVRT){
          float v = fmaxf(y0[((size_t)b*MP + row)*128 + col] + acc[rf][cf][r], 0.f);
          if (EPI == 0) xnext[((size_t)b*MP + row)*160 + 3 + col] = f2bf(v);
          else          outf[((size_t)b*NVRT + row)*128 + col] = v;
        }
      }
    }
}

// ---------------------------------------------------------------- FALLBACK: round-1 k_adj (f32 staging), used if ws too small
template<int EPI>
__global__ __launch_bounds__(256) void k_adj_f32(
    const float* __restrict__ adj,
    const unsigned short* __restrict__ y1p,
    const float* __restrict__ y0,
    unsigned short* __restrict__ xnext,
    float* __restrict__ outf)
{
  __shared__ __align__(16) unsigned short atile[64 * 64];
  int b = blockIdx.y, rb = blockIdx.x * 64;
  int t = threadIdx.x, wave = t >> 6, lane = t & 63;
  f32x4 acc[8];
#pragma unroll
  for (int c = 0; c < 8; c++) acc[c] = (f32x4){0,0,0,0};
  int vrow = t >> 2, chunk = t & 3;
  int grow = rb + vrow;
  bool rvalid = grow < NVRT;
  const float* ap = adj + ((size_t)b * NVRT + grow) * NVRT;
  const unsigned short* y1b = y1p + (size_t)b * (MP/8) * 128 * 8;
  int arow = wave*16 + (lane & 15);
  int sw = (arow & 7) << 4;
  int wsw = (vrow & 7) << 4;

  for (int k0 = 0; k0 < MP; k0 += 64){
    float vals[16];
    int jbase = k0 + chunk * 16;
    if (rvalid && (jbase + 16 <= NVRT)){
      const float2* p = (const float2*)(ap + jbase);
#pragma unroll
      for (int e = 0; e < 8; e++){ float2 f = p[e]; vals[2*e] = f.x; vals[2*e+1] = f.y; }
    } else {
#pragma unroll
      for (int e = 0; e < 16; e++){
        int j = jbase + e;
        vals[e] = (rvalid && j < NVRT) ? ap[j] : 0.f;
      }
    }
    bf16x8 h0, h1;
#pragma unroll
    for (int e = 0; e < 8; e++) h0[e] = (short)f2bf(vals[e]);
#pragma unroll
    for (int e = 0; e < 8; e++) h1[e] = (short)f2bf(vals[8+e]);
    char* basep = (char*)atile + vrow * 128;
    *(bf16x8*)(basep + ((chunk*32     ) ^ wsw)) = h0;
    *(bf16x8*)(basep + ((chunk*32 + 16) ^ wsw)) = h1;
    __syncthreads();
#pragma unroll
    for (int ks = 0; ks < 2; ks++){
      bf16x8 a = *(const bf16x8*)((const char*)atile + arow*128 + ((ks*64 + (lane>>4)*16) ^ sw));
      int kb = k0 + ks*32;
      const unsigned short* bp = y1b + ((size_t)((kb>>3) + (lane>>4)) * 128 + (lane & 15)) * 8;
#pragma unroll
      for (int c = 0; c < 8; c++){
        bf16x8 bb = *(const bf16x8*)(bp + c*128);
        MFMA16(acc[c], a, bb);
      }
    }
    __syncthreads();
  }
#pragma unroll
  for (int c = 0; c < 8; c++){
    int col = 16*c + (lane & 15);
#pragma unroll
    for (int r = 0; r < 4; r++){
      int row = rb + wave*16 + (lane>>4)*4 + r;
      if (row < NVRT){
        float v = fmaxf(y0[((size_t)b*MP + row)*128 + col] + acc[c][r], 0.f);
        if (EPI == 0) xnext[((size_t)b*MP + row)*160 + 3 + col] = f2bf(v);
        else          outf[((size_t)b*NVRT + row)*128 + col] = v;
      }
    }
  }
}

// ---------------------------------------------------------------- new_pos = pos + tanh(feat @ w_lin1 + b_lin1)
__global__ void k_lin1(const float* __restrict__ feat, const float* __restrict__ pos,
                       const float* __restrict__ w, const float* __restrict__ bias,
                       float* __restrict__ opos)
{
  int t = blockIdx.x * blockDim.x + threadIdx.x;
  if (t >= NB * NVRT) return;
  const float* f = feat + (size_t)t * 128;
  float a0 = bias[0], a1 = bias[1], a2 = bias[2];
#pragma unroll 4
  for (int k = 0; k < 128; k++){
    float fv = f[k];
    a0 += fv * w[k*3+0];
    a1 += fv * w[k*3+1];
    a2 += fv * w[k*3+2];
  }
  opos[(size_t)t*3+0] = pos[(size_t)t*3+0] + tanhf(a0);
  opos[(size_t)t*3+1] = pos[(size_t)t*3+1] + tanhf(a1);
  opos[(size_t)t*3+2] = pos[(size_t)t*3+2] + tanhf(a2);
}

// ================================================================ host
extern "C" void kernel_launch(void* const* d_in, const int* in_sizes, int n_in,
                              void* d_out, int out_size, void* d_ws, size_t ws_size,
                              hipStream_t stream)
{
  const float* conv[4] = {(const float*)d_in[0], (const float*)d_in[1],
                          (const float*)d_in[2], (const float*)d_in[3]};
  const float* adj   = (const float*)d_in[4];
  const float* pos   = (const float*)d_in[5];
  const float* vfeat = (const float*)d_in[6];
  const float* wlin0 = (const float*)d_in[7];
  const float* blin0 = (const float*)d_in[8];
  const float* gw[6] = {(const float*)d_in[9],  (const float*)d_in[10],
                        (const float*)d_in[11], (const float*)d_in[12],
                        (const float*)d_in[13], (const float*)d_in[14]};
  const float* wlin1 = (const float*)d_in[15];
  const float* blin1 = (const float*)d_in[16];

  const size_t FT_BYTES   = FT_TOT * 2;                               // 24,084,480
  const size_t META_BYTES = (size_t)NB * NVRT * 32 * 4;               // 2,623,488
  const size_t ADJP_BYTES = (size_t)NB * NRB2 * NKT * 4096;           // 110,166,016
  const size_t PERSIST    = 983040 + 2*73728 + 4*40960 + 12091392
                          + 2*6717440 + 10747904 + 5373952;           // 42,942,464
  bool packed = ws_size >= ADJP_BYTES + PERSIST + 4096;

  char* ws = (char*)d_ws;
  // region 0: ftT + meta live early; packed adjacency overwrites them later
  unsigned short* ftT  = (unsigned short*)ws;
  float*          meta = (float*)(ws + FT_BYTES);
  unsigned short* adjP = (unsigned short*)ws;

  size_t off = packed ? ADJP_BYTES : (FT_BYTES + META_BYTES);
  auto take = [&](size_t bytes)->char* {
    char* p = ws + off;
    off += (bytes + 255) & ~(size_t)255;
    return p;
  };
  unsigned short* wl0p = (unsigned short*)take((size_t)3840*128*2);
  unsigned short* w0p0 = (unsigned short*)take((size_t)288*128*2);
  unsigned short* w1p0 = (unsigned short*)take((size_t)288*128*2);
  unsigned short* w0p1 = (unsigned short*)take((size_t)160*128*2);
  unsigned short* w1p1 = (unsigned short*)take((size_t)160*128*2);
  unsigned short* w0p2 = (unsigned short*)take((size_t)160*128*2);
  unsigned short* w1p2 = (unsigned short*)take((size_t)160*128*2);
  unsigned short* vf   = (unsigned short*)take((size_t)NB*MP*288*2);
  unsigned short* x1   = (unsigned short*)take((size_t)NB*MP*160*2);
  unsigned short* x2   = (unsigned short*)take((size_t)NB*MP*160*2);
  float*          y0   = (float*)take((size_t)NB*MP*128*4);
  unsigned short* y1p  = (unsigned short*)take((size_t)NB*MP*128*2);

  float* out_pos  = (float*)d_out;
  float* out_feat = out_pos + (size_t)NB*NVRT*3;

  // 1. transpose conv maps to channel-last bf16
  const size_t ftBase[4] = {FT_B0, FT_B1, FT_B2, FT_B3};
  const int mC[4]  = {256, 512, 1024, 2048};
  const int mHW[4] = {3136, 784, 196, 49};
  for (int m = 0; m < 4; m++){
    dim3 g((mHW[m] + 31) / 32, (mC[m] + 31) / 32, NB);
    k_transpose<<<g, dim3(32, 8), 0, stream>>>(conv[m], ftT + ftBase[m], mC[m], mHW[m]);
  }
  // 2. bilinear metadata
  k_meta<<<(NB*NVRT + 255)/256, 256, 0, stream>>>(pos, meta);
  // 3. weight packing
  k_packw<<<(3840*128 + 255)/256, 256, 0, stream>>>(wlin0, wl0p, 3840, 128, 3840);
  k_packw<<<(288*128  + 255)/256, 256, 0, stream>>>(gw[0], w0p0, 259, 131, 288);
  k_packw<<<(288*128  + 255)/256, 256, 0, stream>>>(gw[1], w1p0, 259, 131, 288);
  k_packw<<<(160*128  + 255)/256, 256, 0, stream>>>(gw[2], w0p1, 131, 128, 160);
  k_packw<<<(160*128  + 255)/256, 256, 0, stream>>>(gw[3], w1p1, 131, 128, 160);
  k_packw<<<(160*128  + 255)/256, 256, 0, stream>>>(gw[4], w0p2, 131, 128, 160);
  k_packw<<<(160*128  + 255)/256, 256, 0, stream>>>(gw[5], w1p2, 131, 128, 160);
  // 4. vf base cols + zero pads
  k_vf_base<<<dim3(MP, NB), 64, 0, stream>>>(vfeat, pos, vf, x1, x2);
  // 5. fused vert_align + lin0
  k_lin0b<<<dim3(NRB2, NB), 256, 0, stream>>>(ftT, meta, wl0p, blin0, vf);
  // 6. pack adjacency to bf16 tiles (overwrites ftT/meta region — they are dead now)
  if (packed)
    k_adjpack<<<dim3(NKT, NRB2, NB), 256, 0, stream>>>(adj, adjP);
  // 7-12. three graph convs
  k_xw2<288><<<dim3(NRB2, NB), 256, 0, stream>>>(vf, w0p0, w1p0, y0, y1p);
  if (packed) k_adj2<0><<<dim3(NRB2, NB), 256, 0, stream>>>(adjP, y1p, y0, x1, nullptr);
  else        k_adj_f32<0><<<dim3(NRB, NB), 256, 0, stream>>>(adj, y1p, y0, x1, nullptr);
  k_xw2<160><<<dim3(NRB2, NB), 256, 0, stream>>>(x1, w0p1, w1p1, y0, y1p);
  if (packed) k_adj2<0><<<dim3(NRB2, NB), 256, 0, stream>>>(adjP, y1p, y0, x2, nullptr);
  else        k_adj_f32<0><<<dim3(NRB, NB), 256, 0, stream>>>(adj, y1p, y0, x2, nullptr);
  k_xw2<160><<<dim3(NRB2, NB), 256, 0, stream>>>(x2, w0p2, w1p2, y0, y1p);
  if (packed) k_adj2<1><<<dim3(NRB2, NB), 256, 0, stream>>>(adjP, y1p, y0, nullptr, out_feat);
  else        k_adj_f32<1><<<dim3(NRB, NB), 256, 0, stream>>>(adj, y1p, y0, nullptr, out_feat);
  // 13. position head
  k_lin1<<<(NB*NVRT + 255)/256, 256, 0, stream>>>(out_feat, pos, wlin1, blin1, out_pos);
  (void)in_sizes; (void)n_in; (void)out_size; (void)ws_size;
}